// Round 3
// baseline (162.700 us; speedup 1.0000x reference)
//
#include <hip/hip_runtime.h>
#include <hip/hip_bf16.h>

typedef __attribute__((ext_vector_type(8))) short short8;
typedef __attribute__((ext_vector_type(4))) float float4v;

#define LOG2E 1.44269504088896340736f

typedef __attribute__((address_space(1))) const unsigned int gu32;
typedef __attribute__((address_space(3))) unsigned int su32;

__device__ __forceinline__ unsigned short f2bf(float f) {
    unsigned int u = __float_as_uint(f);
    unsigned int r = (u + 0x7fffu + ((u >> 16) & 1u)) >> 16;  // RNE
    return (unsigned short)r;
}

// ---------------------------------------------------------------------------
// Kernel 1: convert Wk|Wq|Wv (fp32) -> combined bf16 Wb[192][1024]
// ---------------------------------------------------------------------------
__global__ void wconv_kernel(const float* __restrict__ Wk, const float* __restrict__ Wq,
                             const float* __restrict__ Wv, unsigned short* __restrict__ Wb) {
    int i = blockIdx.x * 256 + threadIdx.x;
    if (i >= 192 * 1024) return;
    float v;
    if (i < 65536)       v = Wk[i];
    else if (i < 131072) v = Wq[i - 65536];
    else                 v = Wv[i - 131072];
    Wb[i] = f2bf(v);
}

// ---------------------------------------------------------------------------
// Kernel 2: projection GEMM — round-14: BARRIER-FREE WAVE-PRIVATE STAGING.
// R13 post-mortem: counted vmcnt on the 2-phase lockstep loop gained only
// ~3us (proj ~40us). The residual cost is the per-iteration s_barrier convoy
// (m233: 2-phase critical path = stage+vmcnt+barrier; removing one piece
// alone doesn't help). The barrier existed only because staging was
// cooperative (waves read rows staged by OTHER waves). Fix: wave w now READS
// exactly the 48 rows (3 n-tiles) it STAGES -> LDS slab is wave-private ->
// NO s_barrier anywhere. Each wave free-runs on its own counted vmcnt(8):
// outstanding = [stage(kt+1) 6][A(kt+2) 8]; wait leaves the newest 8 (A)
// flying, so stage has ~1 iter cover and A ~2 iters. To keep MFMA count each
// wave covers both 16-row M-halves (12 MFMA/iter); ds_reads HALVE (6/iter,
// each B-frag feeds 2 MFMAs). Issue-order pin (empty memory-clobber asm)
// keeps [stages][A-loads] split so vmcnt counting is exact. Swizzle/banking
// unchanged: read row = wave*48+nn*16+l16 keeps row&7 == l16&7.
// Races: none possible (no cross-wave LDS sharing, no barriers).
// ---------------------------------------------------------------------------
__global__ __launch_bounds__(256) void proj_kernel(
    const float* __restrict__ x, const unsigned short* __restrict__ Wb,
    unsigned short* __restrict__ qs, unsigned short* __restrict__ ks,
    unsigned short* __restrict__ vT) {
    __shared__ unsigned short Bl[2][12288];  // 2 x 192 rows x 64 ushort, 48 KB

    const int tid  = threadIdx.x;
    const int lane = tid & 63;
    const int wave = tid >> 6;
    const int quad = lane >> 4;
    const int l16  = lane & 15;
    const int t0   = blockIdx.x * 32;

    // staging geometry: wave covers regions wave*6..+5; region = 8 rows of
    // 128 B; lane l -> (row l>>3, LDS chunk l&7), source chunk (l&7)^(l>>3)
    const int srow_in = lane >> 3;                 // 0..7
    const int csrc    = (lane & 7) ^ srow_in;      // XOR swizzle source chunk

    const float* xr0 = x + (size_t)(t0 + l16) * 1024;       // M-half 0 row
    const float* xr1 = x + (size_t)(t0 + 16 + l16) * 1024;  // M-half 1 row

    float4v acc[3][2];  // [n-tile][M-half]
#pragma unroll
    for (int nn = 0; nn < 3; nn++)
#pragma unroll
        for (int m = 0; m < 2; m++) acc[nn][m] = (float4v){0.f, 0.f, 0.f, 0.f};

#define STAGE_B(BUF, KN)                                                          \
    {                                                                             \
        _Pragma("unroll")                                                         \
        for (int i = 0; i < 6; i++) {                                             \
            const int region = wave * 6 + i;                                      \
            const int rowg   = region * 8 + srow_in;                              \
            const unsigned short* src = Wb + (size_t)rowg * 1024 + (KN) + csrc * 8; \
            __builtin_amdgcn_global_load_lds((gu32*)src,                          \
                                             (su32*)&Bl[BUF][region * 512],       \
                                             16, 0, 0);                           \
        }                                                                         \
    }

#define LOAD_A(DST, KN)                                        \
    {                                                          \
        DST[0] = *(const float4v*)(xr0 + (KN) + quad * 8);     \
        DST[1] = *(const float4v*)(xr0 + (KN) + quad * 8 + 4); \
        DST[2] = *(const float4v*)(xr0 + (KN) + 32 + quad * 8);     \
        DST[3] = *(const float4v*)(xr0 + (KN) + 32 + quad * 8 + 4); \
        DST[4] = *(const float4v*)(xr1 + (KN) + quad * 8);     \
        DST[5] = *(const float4v*)(xr1 + (KN) + quad * 8 + 4); \
        DST[6] = *(const float4v*)(xr1 + (KN) + 32 + quad * 8);     \
        DST[7] = *(const float4v*)(xr1 + (KN) + 32 + quad * 8 + 4); \
    }

    // prologue: stage tile 0 (oldest in queue), then A tiles 0 and 1
    STAGE_B(0, 0)
    asm volatile("" ::: "memory");  // pin: stages before A-loads
    float4v a0[8], a1[8];
    LOAD_A(a0, 0)
    LOAD_A(a1, 64)

    const int swz = l16 & 7;

#pragma unroll
    for (int kt = 0; kt < 16; kt++) {
        // wait: stage(kt) + A(kt) landed; newest 8 = A(kt+1) may keep flying.
        if (kt < 15) {
            asm volatile("s_waitcnt vmcnt(8)" ::: "memory");
        } else {
            asm volatile("s_waitcnt vmcnt(0)" ::: "memory");
        }
        if (kt < 15) STAGE_B((kt + 1) & 1, (kt + 1) * 64)
        asm volatile("" ::: "memory");  // pin issue order: stages before A-loads
        float4v an[8];
        if (kt < 14) LOAD_A(an, (kt + 2) * 64)

        const unsigned short* Bc = Bl[kt & 1];
#pragma unroll
        for (int kc = 0; kc < 2; kc++) {
            short8 af0, af1;
#pragma unroll
            for (int j = 0; j < 4; j++) af0[j] = (short)f2bf(a0[kc * 2][j]);
#pragma unroll
            for (int j = 0; j < 4; j++) af0[4 + j] = (short)f2bf(a0[kc * 2 + 1][j]);
#pragma unroll
            for (int j = 0; j < 4; j++) af1[j] = (short)f2bf(a0[4 + kc * 2][j]);
#pragma unroll
            for (int j = 0; j < 4; j++) af1[4 + j] = (short)f2bf(a0[4 + kc * 2 + 1][j]);
            const int coff = ((kc * 4 + quad) ^ swz) * 8;
#pragma unroll
            for (int nn = 0; nn < 3; nn++) {
                const int row = wave * 48 + nn * 16 + l16;   // wave-private slab
                const short8 bf = *(const short8*)&Bc[row * 64 + coff];
                acc[nn][0] = __builtin_amdgcn_mfma_f32_16x16x32_bf16(af0, bf, acc[nn][0], 0, 0, 0);
                acc[nn][1] = __builtin_amdgcn_mfma_f32_16x16x32_bf16(af1, bf, acc[nn][1], 0, 0, 0);
            }
        }
        if (kt < 14) {
#pragma unroll
            for (int i = 0; i < 8; i++) { a0[i] = a1[i]; a1[i] = an[i]; }
        } else if (kt < 15) {
#pragma unroll
            for (int i = 0; i < 8; i++) a0[i] = a1[i];
        }
    }
#undef STAGE_B
#undef LOAD_A

    // Epilogue. C layout: row = m*16 + quad*4 + r, col = l16.
    // n-tile mt = wave*3+nn: 0-3 -> ks, 4-7 -> qs (x0.125), 8-11 -> vT.
    const int rowD = t0 + quad * 4;
#pragma unroll
    for (int m = 0; m < 2; m++) {
#pragma unroll
        for (int nn = 0; nn < 3; nn++) {
            const int mt = wave * 3 + nn;
#pragma unroll
            for (int r = 0; r < 4; r++) {
                const int t = rowD + m * 16 + r;
                const float val = acc[nn][m][r];
                if (mt < 4) {
                    ks[(size_t)t * 64 + mt * 16 + l16] = f2bf(val);
                } else if (mt < 8) {
                    qs[(size_t)t * 64 + (mt - 4) * 16 + l16] = f2bf(val * 0.125f);
                } else {
                    const int b = t >> 11, tt = t & 2047;
                    vT[(size_t)b * 131072 + (size_t)((mt - 8) * 16 + l16) * 2048 + tt] = f2bf(val);
                }
            }
        }
    }
}

// ---------------------------------------------------------------------------
// Kernel 3: causal attention v3 — parallel no-max flash [UNCHANGED,
// isolate proj change this round]
// ---------------------------------------------------------------------------
__global__ __launch_bounds__(256) void attn_kernel(
    const unsigned short* __restrict__ qs, const unsigned short* __restrict__ ks,
    const unsigned short* __restrict__ vT, float* __restrict__ out) {
    __shared__ unsigned short Kl[4 * 64 * 72];
    __shared__ unsigned short Vl[64 * 264];
    __shared__ unsigned short P[4][16 * 72];
    __shared__ float Ll[4][16];
    float* Of = (float*)Kl;  // merge buffer aliases Kl: [4][16][68] fp32

    const int tid  = threadIdx.x;
    const int lane = tid & 63;
    const int wave = tid >> 6;
    const int quad = lane >> 4;
    const int l16  = lane & 15;
    const int bx   = blockIdx.x;
    const int b    = bx & 7;
    const int i    = bx >> 3;
    const int qt   = (i & 1) ? (127 - (i >> 1)) : (i >> 1);
    const int t0   = qt * 16;

    const unsigned short* qb = qs + (size_t)b * 131072;
    const unsigned short* kb = ks + (size_t)b * 131072;
    const unsigned short* vb = vT + (size_t)b * 131072;

    const int ksr = tid >> 3;
    const int ksc = (tid & 7) * 8;
    const int vsr = tid >> 5;
    const int vsc = (tid & 31) * 8;

    const int qrow = t0 + l16;
    const short8 qf0 = *(const short8*)(qb + (size_t)qrow * 64 + quad * 8);
    const short8 qf1 = *(const short8*)(qb + (size_t)qrow * 64 + 32 + quad * 8);

    float4v o[4];
#pragma unroll
    for (int ot = 0; ot < 4; ot++) o[ot] = (float4v){0.f, 0.f, 0.f, 0.f};
    float lpart = 0.f;

    const int nkb  = (qt >> 2) + 1;
    const int nsup = (nkb + 3) >> 2;

    for (int s = 0; s < nsup; s++) {
        const int key0 = s * 256;
        __syncthreads();
#pragma unroll
        for (int i2 = 0; i2 < 8; i2++) {
            int kr = key0 + i2 * 32 + ksr; kr = kr < 2047 ? kr : 2047;
            *(short8*)&Kl[(i2 * 32 + ksr) * 72 + ksc] = *(const short8*)(kb + (size_t)kr * 64 + ksc);
        }
#pragma unroll
        for (int i2 = 0; i2 < 8; i2++) {
            const int orow = i2 * 8 + vsr;
            int kc2 = key0 + vsc; kc2 = kc2 < 2040 ? kc2 : 2040;
            *(short8*)&Vl[orow * 264 + vsc] = *(const short8*)(vb + (size_t)orow * 2048 + kc2);
        }
        __syncthreads();

        const int jt = s * 4 + wave;
        if (jt < nkb) {
            const int kbase = wave * 64;
            float4v sv[4];
#pragma unroll
            for (int kt = 0; kt < 4; kt++) {
                const short8 ka = *(const short8*)&Kl[(kbase + kt * 16 + l16) * 72 + quad * 8];
                const short8 kc = *(const short8*)&Kl[(kbase + kt * 16 + l16) * 72 + 32 + quad * 8];
                float4v z = (float4v){0.f, 0.f, 0.f, 0.f};
                z = __builtin_amdgcn_mfma_f32_16x16x32_bf16(ka, qf0, z, 0, 0, 0);
                sv[kt] = __builtin_amdgcn_mfma_f32_16x16x32_bf16(kc, qf1, z, 0, 0, 0);
            }
            if (jt == nkb - 1) {
#pragma unroll
                for (int kt = 0; kt < 4; kt++)
#pragma unroll
                    for (int r = 0; r < 4; r++)
                        if (jt * 64 + kt * 16 + quad * 4 + r > qrow) sv[kt][r] = -1e30f;
            }
#pragma unroll
            for (int kt = 0; kt < 4; kt++) {
                float p0 = exp2f(sv[kt][0] * LOG2E);
                float p1 = exp2f(sv[kt][1] * LOG2E);
                float p2 = exp2f(sv[kt][2] * LOG2E);
                float p3 = exp2f(sv[kt][3] * LOG2E);
                lpart += (p0 + p1) + (p2 + p3);
                unsigned int lo = (unsigned int)f2bf(p0) | ((unsigned int)f2bf(p1) << 16);
                unsigned int hi = (unsigned int)f2bf(p2) | ((unsigned int)f2bf(p3) << 16);
                unsigned long long w = ((unsigned long long)hi << 32) | lo;
                *(unsigned long long*)&P[wave][l16 * 72 + kt * 16 + quad * 4] = w;
            }
#pragma unroll
            for (int kc = 0; kc < 2; kc++) {
                const short8 pf = *(const short8*)&P[wave][l16 * 72 + kc * 32 + quad * 8];
#pragma unroll
                for (int ot = 0; ot < 4; ot++) {
                    const short8 vf = *(const short8*)&Vl[(ot * 16 + l16) * 264 + wave * 64 + kc * 32 + quad * 8];
                    o[ot] = __builtin_amdgcn_mfma_f32_16x16x32_bf16(pf, vf, o[ot], 0, 0, 0);
                }
            }
        }
    }

    lpart += __shfl_xor(lpart, 16);
    lpart += __shfl_xor(lpart, 32);
    __syncthreads();
#pragma unroll
    for (int r = 0; r < 4; r++)
#pragma unroll
        for (int ot = 0; ot < 4; ot++)
            Of[wave * 1088 + (quad * 4 + r) * 68 + ot * 16 + l16] = o[ot][r];
    if (lane < 16) Ll[wave][lane] = lpart;
    __syncthreads();

    {
        const int row = tid >> 4;
        const int c0  = (tid & 15) * 4;
        const float lsum = Ll[0][row] + Ll[1][row] + Ll[2][row] + Ll[3][row];
        float4v v0 = *(const float4v*)&Of[0 * 1088 + row * 68 + c0];
        float4v v1 = *(const float4v*)&Of[1 * 1088 + row * 68 + c0];
        float4v v2 = *(const float4v*)&Of[2 * 1088 + row * 68 + c0];
        float4v v3 = *(const float4v*)&Of[3 * 1088 + row * 68 + c0];
        float4v res;
        const float inv = 1.0f / lsum;
#pragma unroll
        for (int j = 0; j < 4; j++)
            res[j] = ((v0[j] + v1[j]) + (v2[j] + v3[j])) * inv;
        float* ob = out + (size_t)b * 131072 + (size_t)(t0 + row) * 64 + c0;
        *(float4v*)ob = res;
    }
}

// ---------------------------------------------------------------------------
extern "C" void kernel_launch(void* const* d_in, const int* in_sizes, int n_in,
                              void* d_out, int out_size, void* d_ws, size_t ws_size,
                              hipStream_t stream) {
    const float* x  = (const float*)d_in[0];
    const float* Wk = (const float*)d_in[1];
    const float* Wq = (const float*)d_in[2];
    const float* Wv = (const float*)d_in[3];
    float* out = (float*)d_out;

    // Workspace: Wb 384 KB (+pad) | qs 2 MB | ks 2 MB | vT 2 MB
    unsigned short* Wb  = (unsigned short*)d_ws;
    unsigned short* qsb = (unsigned short*)((char*)d_ws + 393216);
    unsigned short* ksb = qsb + 1048576;
    unsigned short* vTb = ksb + 1048576;

    hipLaunchKernelGGL(wconv_kernel, dim3(768), dim3(256), 0, stream, Wk, Wq, Wv, Wb);
    hipLaunchKernelGGL(proj_kernel, dim3(512), dim3(256), 0, stream, x, Wb, qsb, ksb, vTb);
    hipLaunchKernelGGL(attn_kernel, dim3(1024), dim3(256), 0, stream, qsb, ksb, vTb, out);
}

// Round 4
// 159.563 us; speedup vs baseline: 1.0197x; 1.0197x over previous
//
#include <hip/hip_runtime.h>
#include <hip/hip_bf16.h>

typedef __attribute__((ext_vector_type(8))) short short8;
typedef __attribute__((ext_vector_type(4))) float float4v;

#define LOG2E 1.44269504088896340736f

typedef __attribute__((address_space(1))) const unsigned int gu32;
typedef __attribute__((address_space(3))) unsigned int su32;

__device__ __forceinline__ unsigned short f2bf(float f) {
    unsigned int u = __float_as_uint(f);
    unsigned int r = (u + 0x7fffu + ((u >> 16) & 1u)) >> 16;  // RNE
    return (unsigned short)r;
}

// ---------------------------------------------------------------------------
// Kernel 1: convert Wk|Wq|Wv (fp32) -> combined bf16 Wb[192][1024]
// ---------------------------------------------------------------------------
__global__ void wconv_kernel(const float* __restrict__ Wk, const float* __restrict__ Wq,
                             const float* __restrict__ Wv, unsigned short* __restrict__ Wb) {
    int i = blockIdx.x * 256 + threadIdx.x;
    if (i >= 192 * 1024) return;
    float v;
    if (i < 65536)       v = Wk[i];
    else if (i < 131072) v = Wq[i - 65536];
    else                 v = Wv[i - 131072];
    Wb[i] = f2bf(v);
}

// ---------------------------------------------------------------------------
// Kernel 2: projection GEMM — round-15: R13 structure at 8 WAVES (TLP x2).
// R14 post-mortem: barrier-free wave-private staging REGRESSED (40->50us);
// warm-cache replay pass also took 50us (FETCH 6.3MB) -> latency/issue
// bound, not fetch bound; per-wave work had doubled with TLP unchanged at
// 2 waves/SIMD. Lesson: the lever is TLP, not barrier removal. This round:
// revert to R13's verified cooperative-stage + s_barrier + counted-vmcnt
// discipline, but at 512 threads/block (8 waves): 2 blocks/CU x 8 waves =
// 16 waves/CU = 4 waves/SIMD (was 2), and per-wave work HALVES (wave owns
// 3 n-tiles x one M-half: 6 MFMA, 4 A-loads, 16 f2bf, 3 stage-DMAs per
// iter). vmcnt accounting identical to R13: per-iter issue order is
// [3 stage][4 A-loads]; vmcnt(4) at iter top leaves exactly A(kt+1) in
// flight, guarantees stage(kt)+A(kt) landed. WAR: stage(kt+1) overwrites
// the buffer last read at iter kt-1; the barrier at iter kt orders it.
// ---------------------------------------------------------------------------
__global__ __launch_bounds__(512) void proj_kernel(
    const float* __restrict__ x, const unsigned short* __restrict__ Wb,
    unsigned short* __restrict__ qs, unsigned short* __restrict__ ks,
    unsigned short* __restrict__ vT) {
    __shared__ unsigned short Bl[2][12288];  // 2 x 192 rows x 64 ushort, 48 KB

    const int tid  = threadIdx.x;
    const int lane = tid & 63;
    const int wave = tid >> 6;   // 0..7
    const int wg   = wave & 3;   // n-group: 3 n-tiles each
    const int mh   = wave >> 2;  // M-half: 16 rows each
    const int quad = lane >> 4;
    const int l16  = lane & 15;
    const int t0   = blockIdx.x * 32;

    // staging geometry: wave covers regions wave*3..+2; region = 8 rows of
    // 128 B; lane l -> (row l>>3, LDS chunk l&7), source chunk (l&7)^(l>>3)
    const int srow_in = lane >> 3;                 // 0..7
    const int csrc    = (lane & 7) ^ srow_in;      // XOR swizzle source chunk

    const float* xr = x + (size_t)(t0 + mh * 16 + l16) * 1024;

    float4v acc[3];
#pragma unroll
    for (int nn = 0; nn < 3; nn++) acc[nn] = (float4v){0.f, 0.f, 0.f, 0.f};

#define STAGE_B(BUF, KN)                                                          \
    {                                                                             \
        _Pragma("unroll")                                                         \
        for (int i = 0; i < 3; i++) {                                             \
            const int region = wave * 3 + i;                                      \
            const int rowg   = region * 8 + srow_in;                              \
            const unsigned short* src = Wb + (size_t)rowg * 1024 + (KN) + csrc * 8; \
            __builtin_amdgcn_global_load_lds((gu32*)src,                          \
                                             (su32*)&Bl[BUF][region * 512],       \
                                             16, 0, 0);                           \
        }                                                                         \
    }

#define LOAD_A(DST, KN)                                             \
    {                                                               \
        DST[0] = *(const float4v*)(xr + (KN) + quad * 8);           \
        DST[1] = *(const float4v*)(xr + (KN) + quad * 8 + 4);       \
        DST[2] = *(const float4v*)(xr + (KN) + 32 + quad * 8);      \
        DST[3] = *(const float4v*)(xr + (KN) + 32 + quad * 8 + 4);  \
    }

    // prologue: stage tile 0; A-register prefetch tiles 0 and 1 (2-deep)
    STAGE_B(0, 0)
    asm volatile("" ::: "memory");  // pin: stages before A-loads
    float4v a0[4], a1[4];
    LOAD_A(a0, 0)
    LOAD_A(a1, 64)

    const int swz = l16 & 7;

#pragma unroll
    for (int kt = 0; kt < 16; kt++) {
        __builtin_amdgcn_sched_barrier(0);
        // wait: stage(kt) + A(kt) landed; newest 4 = A(kt+1) may keep flying.
        if (kt < 15) {
            asm volatile("s_waitcnt vmcnt(4)" ::: "memory");
        } else {
            asm volatile("s_waitcnt vmcnt(0)" ::: "memory");
        }
        __builtin_amdgcn_s_barrier();
        if (kt < 15) STAGE_B((kt + 1) & 1, (kt + 1) * 64)
        asm volatile("" ::: "memory");  // pin issue order: stages before A-loads
        float4v an[4];
        if (kt < 14) LOAD_A(an, (kt + 2) * 64)

        const unsigned short* Bc = Bl[kt & 1];
#pragma unroll
        for (int kc = 0; kc < 2; kc++) {
            short8 af;
#pragma unroll
            for (int j = 0; j < 4; j++) af[j] = (short)f2bf(a0[kc * 2][j]);
#pragma unroll
            for (int j = 0; j < 4; j++) af[4 + j] = (short)f2bf(a0[kc * 2 + 1][j]);
            const int coff = ((kc * 4 + quad) ^ swz) * 8;
#pragma unroll
            for (int nn = 0; nn < 3; nn++) {
                const int row = (wg * 3 + nn) * 16 + l16;
                const short8 bf = *(const short8*)&Bc[row * 64 + coff];
                acc[nn] = __builtin_amdgcn_mfma_f32_16x16x32_bf16(af, bf, acc[nn], 0, 0, 0);
            }
        }
        if (kt < 14) {
#pragma unroll
            for (int i = 0; i < 4; i++) { a0[i] = a1[i]; a1[i] = an[i]; }
        } else if (kt < 15) {
#pragma unroll
            for (int i = 0; i < 4; i++) a0[i] = a1[i];
        }
    }
#undef STAGE_B
#undef LOAD_A

    // Epilogue. C layout: row = quad*4 + r, col = l16.
    // n-tile mt = wg*3+nn: 0-3 -> ks, 4-7 -> qs (x0.125), 8-11 -> vT.
    const int rowD = t0 + mh * 16 + quad * 4;
#pragma unroll
    for (int nn = 0; nn < 3; nn++) {
        const int mt = wg * 3 + nn;
#pragma unroll
        for (int r = 0; r < 4; r++) {
            const int t = rowD + r;
            const float val = acc[nn][r];
            if (mt < 4) {
                ks[(size_t)t * 64 + mt * 16 + l16] = f2bf(val);
            } else if (mt < 8) {
                qs[(size_t)t * 64 + (mt - 4) * 16 + l16] = f2bf(val * 0.125f);
            } else {
                const int b = t >> 11, tt = t & 2047;
                vT[(size_t)b * 131072 + (size_t)((mt - 8) * 16 + l16) * 2048 + tt] = f2bf(val);
            }
        }
    }
}

// ---------------------------------------------------------------------------
// Kernel 3: causal attention v3 — parallel no-max flash [UNCHANGED,
// isolate proj change this round]
// ---------------------------------------------------------------------------
__global__ __launch_bounds__(256) void attn_kernel(
    const unsigned short* __restrict__ qs, const unsigned short* __restrict__ ks,
    const unsigned short* __restrict__ vT, float* __restrict__ out) {
    __shared__ unsigned short Kl[4 * 64 * 72];
    __shared__ unsigned short Vl[64 * 264];
    __shared__ unsigned short P[4][16 * 72];
    __shared__ float Ll[4][16];
    float* Of = (float*)Kl;  // merge buffer aliases Kl: [4][16][68] fp32

    const int tid  = threadIdx.x;
    const int lane = tid & 63;
    const int wave = tid >> 6;
    const int quad = lane >> 4;
    const int l16  = lane & 15;
    const int bx   = blockIdx.x;
    const int b    = bx & 7;
    const int i    = bx >> 3;
    const int qt   = (i & 1) ? (127 - (i >> 1)) : (i >> 1);
    const int t0   = qt * 16;

    const unsigned short* qb = qs + (size_t)b * 131072;
    const unsigned short* kb = ks + (size_t)b * 131072;
    const unsigned short* vb = vT + (size_t)b * 131072;

    const int ksr = tid >> 3;
    const int ksc = (tid & 7) * 8;
    const int vsr = tid >> 5;
    const int vsc = (tid & 31) * 8;

    const int qrow = t0 + l16;
    const short8 qf0 = *(const short8*)(qb + (size_t)qrow * 64 + quad * 8);
    const short8 qf1 = *(const short8*)(qb + (size_t)qrow * 64 + 32 + quad * 8);

    float4v o[4];
#pragma unroll
    for (int ot = 0; ot < 4; ot++) o[ot] = (float4v){0.f, 0.f, 0.f, 0.f};
    float lpart = 0.f;

    const int nkb  = (qt >> 2) + 1;
    const int nsup = (nkb + 3) >> 2;

    for (int s = 0; s < nsup; s++) {
        const int key0 = s * 256;
        __syncthreads();
#pragma unroll
        for (int i2 = 0; i2 < 8; i2++) {
            int kr = key0 + i2 * 32 + ksr; kr = kr < 2047 ? kr : 2047;
            *(short8*)&Kl[(i2 * 32 + ksr) * 72 + ksc] = *(const short8*)(kb + (size_t)kr * 64 + ksc);
        }
#pragma unroll
        for (int i2 = 0; i2 < 8; i2++) {
            const int orow = i2 * 8 + vsr;
            int kc2 = key0 + vsc; kc2 = kc2 < 2040 ? kc2 : 2040;
            *(short8*)&Vl[orow * 264 + vsc] = *(const short8*)(vb + (size_t)orow * 2048 + kc2);
        }
        __syncthreads();

        const int jt = s * 4 + wave;
        if (jt < nkb) {
            const int kbase = wave * 64;
            float4v sv[4];
#pragma unroll
            for (int kt = 0; kt < 4; kt++) {
                const short8 ka = *(const short8*)&Kl[(kbase + kt * 16 + l16) * 72 + quad * 8];
                const short8 kc = *(const short8*)&Kl[(kbase + kt * 16 + l16) * 72 + 32 + quad * 8];
                float4v z = (float4v){0.f, 0.f, 0.f, 0.f};
                z = __builtin_amdgcn_mfma_f32_16x16x32_bf16(ka, qf0, z, 0, 0, 0);
                sv[kt] = __builtin_amdgcn_mfma_f32_16x16x32_bf16(kc, qf1, z, 0, 0, 0);
            }
            if (jt == nkb - 1) {
#pragma unroll
                for (int kt = 0; kt < 4; kt++)
#pragma unroll
                    for (int r = 0; r < 4; r++)
                        if (jt * 64 + kt * 16 + quad * 4 + r > qrow) sv[kt][r] = -1e30f;
            }
#pragma unroll
            for (int kt = 0; kt < 4; kt++) {
                float p0 = exp2f(sv[kt][0] * LOG2E);
                float p1 = exp2f(sv[kt][1] * LOG2E);
                float p2 = exp2f(sv[kt][2] * LOG2E);
                float p3 = exp2f(sv[kt][3] * LOG2E);
                lpart += (p0 + p1) + (p2 + p3);
                unsigned int lo = (unsigned int)f2bf(p0) | ((unsigned int)f2bf(p1) << 16);
                unsigned int hi = (unsigned int)f2bf(p2) | ((unsigned int)f2bf(p3) << 16);
                unsigned long long w = ((unsigned long long)hi << 32) | lo;
                *(unsigned long long*)&P[wave][l16 * 72 + kt * 16 + quad * 4] = w;
            }
#pragma unroll
            for (int kc = 0; kc < 2; kc++) {
                const short8 pf = *(const short8*)&P[wave][l16 * 72 + kc * 32 + quad * 8];
#pragma unroll
                for (int ot = 0; ot < 4; ot++) {
                    const short8 vf = *(const short8*)&Vl[(ot * 16 + l16) * 264 + wave * 64 + kc * 32 + quad * 8];
                    o[ot] = __builtin_amdgcn_mfma_f32_16x16x32_bf16(pf, vf, o[ot], 0, 0, 0);
                }
            }
        }
    }

    lpart += __shfl_xor(lpart, 16);
    lpart += __shfl_xor(lpart, 32);
    __syncthreads();
#pragma unroll
    for (int r = 0; r < 4; r++)
#pragma unroll
        for (int ot = 0; ot < 4; ot++)
            Of[wave * 1088 + (quad * 4 + r) * 68 + ot * 16 + l16] = o[ot][r];
    if (lane < 16) Ll[wave][lane] = lpart;
    __syncthreads();

    {
        const int row = tid >> 4;
        const int c0  = (tid & 15) * 4;
        const float lsum = Ll[0][row] + Ll[1][row] + Ll[2][row] + Ll[3][row];
        float4v v0 = *(const float4v*)&Of[0 * 1088 + row * 68 + c0];
        float4v v1 = *(const float4v*)&Of[1 * 1088 + row * 68 + c0];
        float4v v2 = *(const float4v*)&Of[2 * 1088 + row * 68 + c0];
        float4v v3 = *(const float4v*)&Of[3 * 1088 + row * 68 + c0];
        float4v res;
        const float inv = 1.0f / lsum;
#pragma unroll
        for (int j = 0; j < 4; j++)
            res[j] = ((v0[j] + v1[j]) + (v2[j] + v3[j])) * inv;
        float* ob = out + (size_t)b * 131072 + (size_t)(t0 + row) * 64 + c0;
        *(float4v*)ob = res;
    }
}

// ---------------------------------------------------------------------------
extern "C" void kernel_launch(void* const* d_in, const int* in_sizes, int n_in,
                              void* d_out, int out_size, void* d_ws, size_t ws_size,
                              hipStream_t stream) {
    const float* x  = (const float*)d_in[0];
    const float* Wk = (const float*)d_in[1];
    const float* Wq = (const float*)d_in[2];
    const float* Wv = (const float*)d_in[3];
    float* out = (float*)d_out;

    // Workspace: Wb 384 KB (+pad) | qs 2 MB | ks 2 MB | vT 2 MB
    unsigned short* Wb  = (unsigned short*)d_ws;
    unsigned short* qsb = (unsigned short*)((char*)d_ws + 393216);
    unsigned short* ksb = qsb + 1048576;
    unsigned short* vTb = ksb + 1048576;

    hipLaunchKernelGGL(wconv_kernel, dim3(768), dim3(256), 0, stream, Wk, Wq, Wv, Wb);
    hipLaunchKernelGGL(proj_kernel, dim3(512), dim3(512), 0, stream, x, Wb, qsb, ksb, vTb);
    hipLaunchKernelGGL(attn_kernel, dim3(1024), dim3(256), 0, stream, qsb, ksb, vTb, out);
}

// Round 5
// 158.177 us; speedup vs baseline: 1.0286x; 1.0088x over previous
//
#include <hip/hip_runtime.h>
#include <hip/hip_bf16.h>

typedef __attribute__((ext_vector_type(8))) short short8;
typedef __attribute__((ext_vector_type(4))) float float4v;

#define LOG2E 1.44269504088896340736f

__device__ __forceinline__ unsigned short f2bf(float f) {
    unsigned int u = __float_as_uint(f);
    unsigned int r = (u + 0x7fffu + ((u >> 16) & 1u)) >> 16;  // RNE
    return (unsigned short)r;
}

// ---------------------------------------------------------------------------
// Kernel 1: convert Wk|Wq|Wv (fp32) -> combined bf16 Wb[192][1024]
// ---------------------------------------------------------------------------
__global__ void wconv_kernel(const float* __restrict__ Wk, const float* __restrict__ Wq,
                             const float* __restrict__ Wv, unsigned short* __restrict__ Wb) {
    int i = blockIdx.x * 256 + threadIdx.x;
    if (i >= 192 * 1024) return;
    float v;
    if (i < 65536)       v = Wk[i];
    else if (i < 131072) v = Wq[i - 65536];
    else                 v = Wv[i - 131072];
    Wb[i] = f2bf(v);
}

// ---------------------------------------------------------------------------
// Kernel 2: projection GEMM — round-16: NO LDS-DMA. Reg-staged B (T14 split).
// Invariance table R11/R13/R14/R15: barrier removal (R14) and TLP doubling
// (R15) both left proj at 40-50us with all pipes idle and warm-cache replay
// unchanged. The single invariant: 768 global_load_lds DMAs per CU, and
// 50us/768 = ~156cy/DMA — the LDS-DMA issue/retire path serializes per CU
// (m97 back-computes to ~180cy/DMA too). Fix: eliminate global_load_lds.
// B staged global->REG at iter top (full compute phase to fly), then
// vmcnt(4) + ds_write_b128 + lgkmcnt(0) + s_barrier (T14 issue-early/
// write-late). ds_write uses the LDS pipe, not the DMA engine.
// vmcnt ledger (issue order per iter: [3 B][4 A], pinned by asm clobbers):
//   at wait of iter kt: queue = A(kt+1)[4] B(kt+1)[3] A(kt+2)[4];
//   vmcnt(4) drains A(kt+1) (used next iter) + B(kt+1) (about to ds_write),
//   leaves A(kt+2) flying (~2 iters cover vs HBM/L3). kt==14 -> vmcnt(0)
//   (tail: no A(16) issued, partial-drain would leave A(15) unwaited).
// XOR swizzle now applied on the WRITE side (we control ds_write addrs):
// source linear (row r, chunk l&7 -> coalesced 128B rows), LDS chunk
// (l&7)^(r&7). Read side unchanged from R15 (verified, 0 conflicts).
// WAR/RAW: single barrier per iter after ds_write orders everything.
// ---------------------------------------------------------------------------
__global__ __launch_bounds__(512, 4) void proj_kernel(
    const float* __restrict__ x, const unsigned short* __restrict__ Wb,
    unsigned short* __restrict__ qs, unsigned short* __restrict__ ks,
    unsigned short* __restrict__ vT) {
    __shared__ unsigned short Bl[2][12288];  // 2 x 192 rows x 64 ushort, 48 KB

    const int tid  = threadIdx.x;
    const int lane = tid & 63;
    const int wave = tid >> 6;   // 0..7
    const int wg   = wave & 3;   // n-group: 3 n-tiles each
    const int mh   = wave >> 2;  // M-half: 16 rows each
    const int quad = lane >> 4;
    const int l16  = lane & 15;
    const int t0   = blockIdx.x * 32;

    // staging geometry: wave covers rows wave*24 .. +23 (3 regions x 8 rows);
    // lane l -> (row offset l>>3, logical chunk l&7). Global source is linear
    // (coalesced 128B rows); LDS destination chunk = (l&7)^(l>>3) (XOR swz).
    const int srow_in = lane >> 3;                 // 0..7
    const int schunk  = lane & 7;                  // logical/source chunk
    const int wchunk  = schunk ^ srow_in;          // swizzled LDS chunk

    const float* xr = x + (size_t)(t0 + mh * 16 + l16) * 1024;

    float4v acc[3];
#pragma unroll
    for (int nn = 0; nn < 3; nn++) acc[nn] = (float4v){0.f, 0.f, 0.f, 0.f};

#define STAGE_LOAD(REG, KN)                                                      \
    {                                                                            \
        _Pragma("unroll")                                                        \
        for (int i = 0; i < 3; i++) {                                            \
            const int rowg = (wave * 3 + i) * 8 + srow_in;                       \
            REG[i] = *(const short8*)(Wb + (size_t)rowg * 1024 + (KN) + schunk * 8); \
        }                                                                        \
    }

#define STAGE_WRITE(BUF, REG)                                                    \
    {                                                                            \
        _Pragma("unroll")                                                        \
        for (int i = 0; i < 3; i++) {                                            \
            const int rowg = (wave * 3 + i) * 8 + srow_in;                       \
            *(short8*)&Bl[BUF][rowg * 64 + wchunk * 8] = REG[i];                 \
        }                                                                        \
    }

#define LOAD_A(DST, KN)                                             \
    {                                                               \
        DST[0] = *(const float4v*)(xr + (KN) + quad * 8);           \
        DST[1] = *(const float4v*)(xr + (KN) + quad * 8 + 4);       \
        DST[2] = *(const float4v*)(xr + (KN) + 32 + quad * 8);      \
        DST[3] = *(const float4v*)(xr + (KN) + 32 + quad * 8 + 4);  \
    }

    // prologue: A tiles 0,1 to regs; B tile 0 to regs -> LDS buf0; full drain.
    float4v a0[4], a1[4];
    short8 breg[3];
    LOAD_A(a0, 0)
    LOAD_A(a1, 64)
    STAGE_LOAD(breg, 0)
    asm volatile("s_waitcnt vmcnt(0)" ::: "memory");
    STAGE_WRITE(0, breg)
    asm volatile("s_waitcnt lgkmcnt(0)" ::: "memory");
    __builtin_amdgcn_s_barrier();

#pragma unroll
    for (int kt = 0; kt < 16; kt++) {
        // issue next B tile's global loads FIRST (oldest in vm queue)
        if (kt < 15) STAGE_LOAD(breg, (kt + 1) * 64)
        asm volatile("" ::: "memory");  // pin: B-loads before A-loads
        float4v an[4];
        if (kt < 14) LOAD_A(an, (kt + 2) * 64)
        asm volatile("" ::: "memory");  // pin: vm issue group closed

        // compute tile kt from LDS buf (kt&1) using a0 = A(kt)
        const unsigned short* Bc = Bl[kt & 1];
#pragma unroll
        for (int kc = 0; kc < 2; kc++) {
            short8 af;
#pragma unroll
            for (int j = 0; j < 4; j++) af[j] = (short)f2bf(a0[kc * 2][j]);
#pragma unroll
            for (int j = 0; j < 4; j++) af[4 + j] = (short)f2bf(a0[kc * 2 + 1][j]);
            const int coff = ((kc * 4 + quad) ^ (l16 & 7)) * 8;
#pragma unroll
            for (int nn = 0; nn < 3; nn++) {
                const int row = (wg * 3 + nn) * 16 + l16;
                const short8 bf = *(const short8*)&Bc[row * 64 + coff];
                acc[nn] = __builtin_amdgcn_mfma_f32_16x16x32_bf16(af, bf, acc[nn], 0, 0, 0);
            }
        }

        if (kt < 15) {
            // drain B(kt+1) (+A(kt+1)); keep A(kt+2) flying. Tail kt==14:
            // no A(16) in queue, partial drain would strand A(15) -> vmcnt(0).
            if (kt < 14) {
                asm volatile("s_waitcnt vmcnt(4)" ::: "memory");
            } else {
                asm volatile("s_waitcnt vmcnt(0)" ::: "memory");
            }
            STAGE_WRITE((kt + 1) & 1, breg)
            asm volatile("s_waitcnt lgkmcnt(0)" ::: "memory");
            __builtin_amdgcn_s_barrier();
        }

        if (kt < 14) {
#pragma unroll
            for (int i = 0; i < 4; i++) { a0[i] = a1[i]; a1[i] = an[i]; }
        } else if (kt < 15) {
#pragma unroll
            for (int i = 0; i < 4; i++) a0[i] = a1[i];
        }
    }
#undef STAGE_LOAD
#undef STAGE_WRITE
#undef LOAD_A

    // Epilogue. C layout: row = quad*4 + r, col = l16.
    // n-tile mt = wg*3+nn: 0-3 -> ks, 4-7 -> qs (x0.125), 8-11 -> vT.
    const int rowD = t0 + mh * 16 + quad * 4;
#pragma unroll
    for (int nn = 0; nn < 3; nn++) {
        const int mt = wg * 3 + nn;
#pragma unroll
        for (int r = 0; r < 4; r++) {
            const int t = rowD + r;
            const float val = acc[nn][r];
            if (mt < 4) {
                ks[(size_t)t * 64 + mt * 16 + l16] = f2bf(val);
            } else if (mt < 8) {
                qs[(size_t)t * 64 + (mt - 4) * 16 + l16] = f2bf(val * 0.125f);
            } else {
                const int b = t >> 11, tt = t & 2047;
                vT[(size_t)b * 131072 + (size_t)((mt - 8) * 16 + l16) * 2048 + tt] = f2bf(val);
            }
        }
    }
}

// ---------------------------------------------------------------------------
// Kernel 3: causal attention v3 — parallel no-max flash [UNCHANGED,
// isolate proj change this round]
// ---------------------------------------------------------------------------
__global__ __launch_bounds__(256) void attn_kernel(
    const unsigned short* __restrict__ qs, const unsigned short* __restrict__ ks,
    const unsigned short* __restrict__ vT, float* __restrict__ out) {
    __shared__ unsigned short Kl[4 * 64 * 72];
    __shared__ unsigned short Vl[64 * 264];
    __shared__ unsigned short P[4][16 * 72];
    __shared__ float Ll[4][16];
    float* Of = (float*)Kl;  // merge buffer aliases Kl: [4][16][68] fp32

    const int tid  = threadIdx.x;
    const int lane = tid & 63;
    const int wave = tid >> 6;
    const int quad = lane >> 4;
    const int l16  = lane & 15;
    const int bx   = blockIdx.x;
    const int b    = bx & 7;
    const int i    = bx >> 3;
    const int qt   = (i & 1) ? (127 - (i >> 1)) : (i >> 1);
    const int t0   = qt * 16;

    const unsigned short* qb = qs + (size_t)b * 131072;
    const unsigned short* kb = ks + (size_t)b * 131072;
    const unsigned short* vb = vT + (size_t)b * 131072;

    const int ksr = tid >> 3;
    const int ksc = (tid & 7) * 8;
    const int vsr = tid >> 5;
    const int vsc = (tid & 31) * 8;

    const int qrow = t0 + l16;
    const short8 qf0 = *(const short8*)(qb + (size_t)qrow * 64 + quad * 8);
    const short8 qf1 = *(const short8*)(qb + (size_t)qrow * 64 + 32 + quad * 8);

    float4v o[4];
#pragma unroll
    for (int ot = 0; ot < 4; ot++) o[ot] = (float4v){0.f, 0.f, 0.f, 0.f};
    float lpart = 0.f;

    const int nkb  = (qt >> 2) + 1;
    const int nsup = (nkb + 3) >> 2;

    for (int s = 0; s < nsup; s++) {
        const int key0 = s * 256;
        __syncthreads();
#pragma unroll
        for (int i2 = 0; i2 < 8; i2++) {
            int kr = key0 + i2 * 32 + ksr; kr = kr < 2047 ? kr : 2047;
            *(short8*)&Kl[(i2 * 32 + ksr) * 72 + ksc] = *(const short8*)(kb + (size_t)kr * 64 + ksc);
        }
#pragma unroll
        for (int i2 = 0; i2 < 8; i2++) {
            const int orow = i2 * 8 + vsr;
            int kc2 = key0 + vsc; kc2 = kc2 < 2040 ? kc2 : 2040;
            *(short8*)&Vl[orow * 264 + vsc] = *(const short8*)(vb + (size_t)orow * 2048 + kc2);
        }
        __syncthreads();

        const int jt = s * 4 + wave;
        if (jt < nkb) {
            const int kbase = wave * 64;
            float4v sv[4];
#pragma unroll
            for (int kt = 0; kt < 4; kt++) {
                const short8 ka = *(const short8*)&Kl[(kbase + kt * 16 + l16) * 72 + quad * 8];
                const short8 kc = *(const short8*)&Kl[(kbase + kt * 16 + l16) * 72 + 32 + quad * 8];
                float4v z = (float4v){0.f, 0.f, 0.f, 0.f};
                z = __builtin_amdgcn_mfma_f32_16x16x32_bf16(ka, qf0, z, 0, 0, 0);
                sv[kt] = __builtin_amdgcn_mfma_f32_16x16x32_bf16(kc, qf1, z, 0, 0, 0);
            }
            if (jt == nkb - 1) {
#pragma unroll
                for (int kt = 0; kt < 4; kt++)
#pragma unroll
                    for (int r = 0; r < 4; r++)
                        if (jt * 64 + kt * 16 + quad * 4 + r > qrow) sv[kt][r] = -1e30f;
            }
#pragma unroll
            for (int kt = 0; kt < 4; kt++) {
                float p0 = exp2f(sv[kt][0] * LOG2E);
                float p1 = exp2f(sv[kt][1] * LOG2E);
                float p2 = exp2f(sv[kt][2] * LOG2E);
                float p3 = exp2f(sv[kt][3] * LOG2E);
                lpart += (p0 + p1) + (p2 + p3);
                unsigned int lo = (unsigned int)f2bf(p0) | ((unsigned int)f2bf(p1) << 16);
                unsigned int hi = (unsigned int)f2bf(p2) | ((unsigned int)f2bf(p3) << 16);
                unsigned long long w = ((unsigned long long)hi << 32) | lo;
                *(unsigned long long*)&P[wave][l16 * 72 + kt * 16 + quad * 4] = w;
            }
#pragma unroll
            for (int kc = 0; kc < 2; kc++) {
                const short8 pf = *(const short8*)&P[wave][l16 * 72 + kc * 32 + quad * 8];
#pragma unroll
                for (int ot = 0; ot < 4; ot++) {
                    const short8 vf = *(const short8*)&Vl[(ot * 16 + l16) * 264 + wave * 64 + kc * 32 + quad * 8];
                    o[ot] = __builtin_amdgcn_mfma_f32_16x16x32_bf16(pf, vf, o[ot], 0, 0, 0);
                }
            }
        }
    }

    lpart += __shfl_xor(lpart, 16);
    lpart += __shfl_xor(lpart, 32);
    __syncthreads();
#pragma unroll
    for (int r = 0; r < 4; r++)
#pragma unroll
        for (int ot = 0; ot < 4; ot++)
            Of[wave * 1088 + (quad * 4 + r) * 68 + ot * 16 + l16] = o[ot][r];
    if (lane < 16) Ll[wave][lane] = lpart;
    __syncthreads();

    {
        const int row = tid >> 4;
        const int c0  = (tid & 15) * 4;
        const float lsum = Ll[0][row] + Ll[1][row] + Ll[2][row] + Ll[3][row];
        float4v v0 = *(const float4v*)&Of[0 * 1088 + row * 68 + c0];
        float4v v1 = *(const float4v*)&Of[1 * 1088 + row * 68 + c0];
        float4v v2 = *(const float4v*)&Of[2 * 1088 + row * 68 + c0];
        float4v v3 = *(const float4v*)&Of[3 * 1088 + row * 68 + c0];
        float4v res;
        const float inv = 1.0f / lsum;
#pragma unroll
        for (int j = 0; j < 4; j++)
            res[j] = ((v0[j] + v1[j]) + (v2[j] + v3[j])) * inv;
        float* ob = out + (size_t)b * 131072 + (size_t)(t0 + row) * 64 + c0;
        *(float4v*)ob = res;
    }
}

// ---------------------------------------------------------------------------
extern "C" void kernel_launch(void* const* d_in, const int* in_sizes, int n_in,
                              void* d_out, int out_size, void* d_ws, size_t ws_size,
                              hipStream_t stream) {
    const float* x  = (const float*)d_in[0];
    const float* Wk = (const float*)d_in[1];
    const float* Wq = (const float*)d_in[2];
    const float* Wv = (const float*)d_in[3];
    float* out = (float*)d_out;

    // Workspace: Wb 384 KB (+pad) | qs 2 MB | ks 2 MB | vT 2 MB
    unsigned short* Wb  = (unsigned short*)d_ws;
    unsigned short* qsb = (unsigned short*)((char*)d_ws + 393216);
    unsigned short* ksb = qsb + 1048576;
    unsigned short* vTb = ksb + 1048576;

    hipLaunchKernelGGL(wconv_kernel, dim3(768), dim3(256), 0, stream, Wk, Wq, Wv, Wb);
    hipLaunchKernelGGL(proj_kernel, dim3(512), dim3(512), 0, stream, x, Wb, qsb, ksb, vTb);
    hipLaunchKernelGGL(attn_kernel, dim3(1024), dim3(256), 0, stream, qsb, ksb, vTb, out);
}